// Round 6
// baseline (137.841 us; speedup 1.0000x reference)
//
#include <hip/hip_runtime.h>

#define HID 1024
#define RANK 16
#define NSEG 64
#define NXCD 8

// d_ws layout (ints): [0:64) base, [64:128) cursor, [128:128+slots) sorted
// sorted entry: (seg << 14) | token_id ; -1 = invalid slot

__global__ __launch_bounds__(1024) void k1_hist(
    const int* __restrict__ seg, int N,
    int* __restrict__ base_c, int* __restrict__ cursor,
    int* __restrict__ sorted, int slots)
{
    __shared__ int hist[NSEG];
    __shared__ int pbase[NSEG];
    __shared__ int paddedTotal;
    const int tid = threadIdx.x;
    if (tid < NSEG) hist[tid] = 0;
    __syncthreads();
    for (int i = tid; i < N; i += 1024) atomicAdd(&hist[seg[i]], 1);
    __syncthreads();
    if (tid == 0) {
        int run = 0;
        for (int s = 0; s < NSEG; ++s) { pbase[s] = run; run += (hist[s] + 3) & ~3; }
        paddedTotal = run;
    }
    __syncthreads();
    if (tid < NSEG) {
        base_c[tid] = pbase[tid];
        cursor[tid] = 0;
        const int c0 = hist[tid], c1 = (hist[tid] + 3) & ~3;
        for (int k = c0; k < c1; ++k) sorted[pbase[tid] + k] = -1;  // <=3 pads
    }
    for (int i = paddedTotal + tid; i < slots; i += 1024) sorted[i] = -1;
}

__global__ __launch_bounds__(256) void k2_scatter(
    const int* __restrict__ seg, int N,
    const int* __restrict__ base_c, int* __restrict__ cursor,
    int* __restrict__ sorted)
{
    const int i = blockIdx.x * 256 + threadIdx.x;
    if (i < N) {
        const int s = seg[i];
        const int pos = atomicAdd(&cursor[s], 1);
        sorted[base_c[s] + pos] = (s << 14) | i;
    }
}

__global__ __launch_bounds__(256) void lora_apply(
    const float* __restrict__ x,      // [N, H]
    const int*   __restrict__ sorted, // [slots]
    const float* __restrict__ A,      // [S, H, R]
    const float* __restrict__ B,      // [S, R, H]
    const float* __restrict__ bias,   // [S, H]
    float*       __restrict__ out,    // [N, H]
    int tilesPerXcd)
{
    // chunked XCD swizzle: consecutive tiles (same segment run) share an XCD L2
    const int work = (blockIdx.x & (NXCD - 1)) * tilesPerXcd + (blockIdx.x >> 3);
    const int tid  = threadIdx.x;
    const int lane = tid & 63;
    const int wave = tid >> 6;

    __shared__ float red[4][16][68];
    __shared__ float inter_lds[4][RANK];

    int e[4];
    #pragma unroll
    for (int j = 0; j < 4; ++j) e[j] = sorted[work * 4 + j];
    if (e[0] < 0) return;                      // tail tile, uniform exit
    const int s = e[0] >> 14;

    int  n[4];
    bool valid[4];
    #pragma unroll
    for (int j = 0; j < 4; ++j) {
        valid[j] = e[j] >= 0;
        n[j] = (valid[j] ? e[j] : e[0]) & 16383;
    }

    // A + bias hoist (per tile)
    const float4* A4 = (const float4*)(A + (size_t)s * HID * RANK);
    float4 av[4][4];
    #pragma unroll
    for (int jh = 0; jh < 4; ++jh)
        #pragma unroll
        for (int q = 0; q < 4; ++q)
            av[jh][q] = A4[(size_t)(tid * 4 + jh) * (RANK / 4) + q];
    const float4 bia = ((const float4*)(bias + (size_t)s * HID))[tid];

    // Phase 1: inter[j][r] = sum_h B[s][r][h] * x[n[j]][h]
    // wave owns r = 4*wave+rr ; coalesced float4 loads [k*64 + lane]
    float4 xv[4][4];
    #pragma unroll
    for (int j = 0; j < 4; ++j) {
        const float4* xr = (const float4*)(x + (size_t)n[j] * HID);
        #pragma unroll
        for (int k = 0; k < 4; ++k) xv[j][k] = xr[k * 64 + lane];
    }

    const float4* B4 = (const float4*)(B + (size_t)s * RANK * HID);
    float acc[4][4];
    #pragma unroll
    for (int rr = 0; rr < 4; ++rr)
        #pragma unroll
        for (int j = 0; j < 4; ++j) acc[rr][j] = 0.f;

    #pragma unroll
    for (int rr = 0; rr < 4; ++rr) {
        const float4* Br = B4 + (size_t)(wave * 4 + rr) * (HID / 4);
        #pragma unroll
        for (int k = 0; k < 4; ++k) {
            float4 b = Br[k * 64 + lane];
            #pragma unroll
            for (int j = 0; j < 4; ++j)
                acc[rr][j] += b.x * xv[j][k].x + b.y * xv[j][k].y
                            + b.z * xv[j][k].z + b.w * xv[j][k].w;
        }
    }

    // wave-local LDS transpose-reduce
    #pragma unroll
    for (int rr = 0; rr < 4; ++rr)
        #pragma unroll
        for (int j = 0; j < 4; ++j)
            red[wave][rr * 4 + j][lane] = acc[rr][j];

    const int v = lane & 15;
    const int q = lane >> 4;
    const float4* rp = (const float4*)&red[wave][v][q * 16];
    float4 r0 = rp[0], r1 = rp[1], r2 = rp[2], r3 = rp[3];
    float sum = ((r0.x + r0.y) + (r0.z + r0.w))
              + ((r1.x + r1.y) + (r1.z + r1.w))
              + ((r2.x + r2.y) + (r2.z + r2.w))
              + ((r3.x + r3.y) + (r3.z + r3.w));
    sum += __shfl_xor(sum, 16, 64);
    sum += __shfl_xor(sum, 32, 64);
    if (lane < 16) inter_lds[v & 3][wave * 4 + (v >> 2)] = sum;
    __syncthreads();                           // the only barrier

    // Phase 2: out[n[j]][h] = sum_r A[s][h][r]*inter[j][r] + bias
    #pragma unroll
    for (int j = 0; j < 4; ++j) {
        const float4* I4 = (const float4*)inter_lds[j];
        float4 iv[4];
        #pragma unroll
        for (int qq = 0; qq < 4; ++qq) iv[qq] = I4[qq];
        float4 o = bia;
        float* op = (float*)&o;
        #pragma unroll
        for (int jh = 0; jh < 4; ++jh) {
            float a = 0.f;
            #pragma unroll
            for (int qq = 0; qq < 4; ++qq)
                a += av[jh][qq].x * iv[qq].x + av[jh][qq].y * iv[qq].y
                   + av[jh][qq].z * iv[qq].z + av[jh][qq].w * iv[qq].w;
            op[jh] += a;
        }
        if (valid[j])
            ((float4*)(out + (size_t)n[j] * HID))[tid] = o;
    }
}

extern "C" void kernel_launch(void* const* d_in, const int* in_sizes, int n_in,
                              void* d_out, int out_size, void* d_ws, size_t ws_size,
                              hipStream_t stream) {
    const float* x    = (const float*)d_in[0];
    const int*   seg  = (const int*)d_in[1];
    const float* A    = (const float*)d_in[2];
    const float* B    = (const float*)d_in[3];
    const float* bias = (const float*)d_in[4];
    float* out = (float*)d_out;

    const int N = in_sizes[1];

    // tiles: covers worst-case per-segment padding; rounded to multiple of 8
    int tiles = ((N + 3) / 4 + NSEG + 7) & ~7;        // 2112 for N=8192
    const int slots = tiles * 4;

    int* wsi    = (int*)d_ws;
    int* base_c = wsi;
    int* cursor = wsi + NSEG;
    int* sorted = wsi + 2 * NSEG;

    k1_hist   <<<1, 1024, 0, stream>>>(seg, N, base_c, cursor, sorted, slots);
    k2_scatter<<<(N + 255) / 256, 256, 0, stream>>>(seg, N, base_c, cursor, sorted);
    lora_apply<<<tiles, 256, 0, stream>>>(x, sorted, A, B, bias, out, tiles / NXCD);
}